// Round 8
// baseline (94.985 us; speedup 1.0000x reference)
//
#include <hip/hip_runtime.h>

// CfdInterpolateMeshToGrid: B=8, M=8192 mesh pts/batch, G=2048 grid pts/batch,
// D=2, C=64, K=3.  out[g,c] = sum_k w_k * x[nn_k(g), c] / sum_k w_k,
// w_k = 1 / max(d2_k, 1e-16), d2 = (g2 + m2) - 2*dot.
//
// NUMERICS (locked by rounds 1-5 — DO NOT CHANGE):
//   #pragma clang fp contract(off) in every kernel, plus exactly:
//     m2  = (mx*mx) + (my*my)           // unfused
//     g2  = (gx*gx) + (gy*gy)           // unfused
//     p0  = gx*mx; dot = fmaf(gy,my,p0) // fma-ascending k-contraction (BLAS)
//     t   = g2 + m2
//     d2  = fmaf(-2, dot, t)            // == t - (2*dot) bit-exactly
//   Top-3 by strict < on d2, lowest-global-index wins ties (stable top_k).
//
// SCHEDULE (round 8): round-7 knn_scan was 54us: the per-lane gated insert
// was IF-CONVERTED (13.6 VALU insts/pair, cndmask chain every iter) and
// single-chain latency-bound (VALUBusy 43%, occ 37%). Fixes:
//  (a) wave-uniform gate `if (__any(hit))` -> scalar s_cbranch, insert chain
//      only executes when some lane hits (~5-10% of iterations);
//  (b) S2=32 -> 2048 blocks = 32 waves/CU (TLP hides LDS latency);
//  (c) merge handles 96 candidates, 2 slots/lane + 6-step butterfly.

#define BLK 256
#define S1  32          // phase-1 chunks (chunkLen 256)
#define S2  32          // phase-2 chunks (chunkLen 256)
#define NG1 2           // grid points per thread in phase 1
#define PADIDX 0x7FFFFFFF

// Phase 1: branchless chunk-min of d2. block = (gb, b, s).
__global__ void knn_min(const float* __restrict__ mesh_pos,
                        const float* __restrict__ grid_pos,
                        float* __restrict__ mins,
                        int M, int G, int Gt, int chunkLen)
{
#pragma clang fp contract(off)
    __shared__ float4 lds[256];
    const int gb = blockIdx.x, b = blockIdx.y, s = blockIdx.z;
    const int tid = threadIdx.x;

    const float2* mp = (const float2*)mesh_pos + (size_t)b * M + (size_t)s * chunkLen;
    for (int j = tid; j < chunkLen; j += BLK) {
        float2 m = mp[j];
        float m2 = (m.x * m.x) + (m.y * m.y);   // unfused (contract off)
        lds[j] = make_float4(m.x, m.y, m2, 0.0f);
    }
    __syncthreads();

    const int g0 = b * G + gb * (BLK * NG1) + tid;
    const int g1 = g0 + BLK;
    const float2 gpA = ((const float2*)grid_pos)[g0];
    const float2 gpB = ((const float2*)grid_pos)[g1];
    const float gxA = gpA.x, gyA = gpA.y, gxB = gpB.x, gyB = gpB.y;
    const float g2A = (gxA * gxA) + (gyA * gyA);
    const float g2B = (gxB * gxB) + (gyB * gyB);

    float mnA = 1e30f, mnB = 1e30f;
    #pragma unroll 8
    for (int j = 0; j < chunkLen; ++j) {
        float4 m = lds[j];
        float p0a  = gxA * m.x;
        float dota = fmaf(gyA, m.y, p0a);
        float ta   = g2A + m.z;
        float d2a  = fmaf(-2.0f, dota, ta);
        mnA = fminf(mnA, d2a);
        float p0b  = gxB * m.x;
        float dotb = fmaf(gyB, m.y, p0b);
        float tb   = g2B + m.z;
        float d2b  = fmaf(-2.0f, dotb, tb);
        mnB = fminf(mnB, d2b);
    }
    mins[(size_t)s * Gt + g0] = mnA;
    mins[(size_t)s * Gt + g1] = mnB;
}

// Bound: per grid point, 3rd-smallest of the S1 chunk mins. Provable upper
// bound on the 3rd-NN d2: the 3 best chunk-mins belong to 3 distinct points.
__global__ void knn_bound(const float* __restrict__ mins,
                          float* __restrict__ bound, int Gt)
{
    const int g = blockIdx.x * BLK + threadIdx.x;
    float b0 = 1e30f, b1 = 1e30f, b2 = 1e30f;
    #pragma unroll
    for (int s = 0; s < S1; ++s) {
        float v = mins[(size_t)s * Gt + g];
        if (v < b2) {
            if (v < b1) { b2 = b1; if (v < b0) { b1 = b0; b0 = v; } else b1 = v; }
            else        { b2 = v; }
        }
    }
    bound[g] = b2;
}

// Phase 2: gated rescan; per-chunk top-3 of candidates with d2 <= bound.
// Wave-uniform gate keeps the insert chain out of the hot loop.
__global__ void knn_scan(const float* __restrict__ mesh_pos,
                         const float* __restrict__ grid_pos,
                         const float* __restrict__ bound,
                         float* __restrict__ cd2,
                         int* __restrict__ cidx,
                         int M, int G, int Gt, int chunkLen)
{
#pragma clang fp contract(off)
    __shared__ float4 lds[256];
    const int gb = blockIdx.x, b = blockIdx.y, s = blockIdx.z;
    const int tid = threadIdx.x;

    const float2* mp = (const float2*)mesh_pos + (size_t)b * M + (size_t)s * chunkLen;
    for (int j = tid; j < chunkLen; j += BLK) {
        float2 m = mp[j];
        float m2 = (m.x * m.x) + (m.y * m.y);   // unfused — identical to phase 1
        lds[j] = make_float4(m.x, m.y, m2, 0.0f);
    }
    __syncthreads();

    const int g = b * G + gb * BLK + tid;
    const float2 gp = ((const float2*)grid_pos)[g];
    const float gx = gp.x, gy = gp.y;
    const float g2 = (gx * gx) + (gy * gy);
    const float bnd = bound[g];

    float b0 = 1e30f, b1 = 1e30f, b2 = 1e30f;
    int   i0 = PADIDX, i1 = PADIDX, i2 = PADIDX;

    #pragma unroll 4
    for (int j = 0; j < chunkLen; ++j) {
        float4 m  = lds[j];
        float p0  = gx * m.x;
        float dot = fmaf(gy, m.y, p0);
        float t   = g2 + m.z;
        float d2  = fmaf(-2.0f, dot, t);
        const bool hit = (d2 <= bnd);
        if (__any(hit)) {            // wave-uniform -> real s_cbranch, rare
            if (hit) {
                if (d2 < b2) {
                    if (d2 < b1) {
                        b2 = b1; i2 = i1;
                        if (d2 < b0) { b1 = b0; i1 = i0; b0 = d2; i0 = j; }
                        else         { b1 = d2; i1 = j; }
                    } else           { b2 = d2; i2 = j; }
                }
            }
        }
    }

    const int joff = s * chunkLen;
    const size_t base = ((size_t)s * Gt + g) * 3;
    cd2[base + 0] = b0; cidx[base + 0] = (i0 == PADIDX) ? PADIDX : i0 + joff;
    cd2[base + 1] = b1; cidx[base + 1] = (i1 == PADIDX) ? PADIDX : i1 + joff;
    cd2[base + 2] = b2; cidx[base + 2] = (i2 == PADIDX) ? PADIDX : i2 + joff;
}

// Merge + gather: one wave per grid point. 96 candidates = 2 slots/lane;
// 3 rounds of {local lex-min, 6-step butterfly lex-min, pop owner}.
// (d2, idx) lex order reproduces stable top_k (idx unique for real entries).
__global__ void knn_merge(const float* __restrict__ x,
                          const float* __restrict__ cd2,
                          const int* __restrict__ cidx,
                          float* __restrict__ out,
                          int M, int G, int Gt)
{
#pragma clang fp contract(off)
    const int tid  = threadIdx.x;
    const int g    = blockIdx.x * 4 + (tid >> 6);
    const int lane = tid & 63;

    // slot 0: entry e=lane (0..63); slot 1: entry e=64+lane (lane<32)
    float da = 1e30f, db = 1e30f;
    int   ia = PADIDX, ib = PADIDX;
    {
        const int e = lane;              // always valid (< 96)
        const int s = e / 3, k = e - 3 * s;
        const size_t a = ((size_t)s * Gt + g) * 3 + k;
        da = cd2[a]; ia = cidx[a];
    }
    if (lane < 32) {
        const int e = 64 + lane;
        const int s = e / 3, k = e - 3 * s;
        const size_t a = ((size_t)s * Gt + g) * 3 + k;
        db = cd2[a]; ib = cidx[a];
    }

    float wd2[3]; int widx[3];
    #pragma unroll
    for (int r = 0; r < 3; ++r) {
        float rd; int ri;
        if (db < da || (db == da && ib < ia)) { rd = db; ri = ib; }
        else                                  { rd = da; ri = ia; }
        #pragma unroll
        for (int off = 32; off; off >>= 1) {
            float od = __shfl_xor(rd, off, 64);
            int   oi = __shfl_xor(ri, off, 64);
            if (od < rd || (od == rd && oi < ri)) { rd = od; ri = oi; }
        }
        wd2[r] = rd; widx[r] = ri;
        if (da == rd && ia == ri)      { da = 1e30f; ia = PADIDX; }
        else if (db == rd && ib == ri) { db = 1e30f; ib = PADIDX; }
    }

    const int b = g / G;
    const float w0 = 1.0f / fmaxf(wd2[0], 1e-16f);
    const float w1 = 1.0f / fmaxf(wd2[1], 1e-16f);
    const float w2 = 1.0f / fmaxf(wd2[2], 1e-16f);

    const size_t rowBase = (size_t)b * M * 64;
    const float x0 = x[rowBase + (size_t)widx[0] * 64 + lane];
    const float x1 = x[rowBase + (size_t)widx[1] * 64 + lane];
    const float x2 = x[rowBase + (size_t)widx[2] * 64 + lane];

    const float num = ((w0 * x0) + (w1 * x1)) + (w2 * x2);  // unfused
    const float den = (w0 + w1) + w2;
    out[(size_t)g * 64 + lane] = num / den;
}

extern "C" void kernel_launch(void* const* d_in, const int* in_sizes, int n_in,
                              void* d_out, int out_size, void* d_ws, size_t ws_size,
                              hipStream_t stream) {
    const float* x        = (const float*)d_in[0];
    const float* mesh_pos = (const float*)d_in[1];
    const float* grid_pos = (const float*)d_in[2];
    // d_in[3] = batch_idx (int64) — contiguous repeat layout, unused.

    const int N  = in_sizes[1] / 2;   // 65536
    const int Gt = in_sizes[2] / 2;   // 16384
    const int B  = 8;
    const int M  = N / B;             // 8192
    const int G  = Gt / B;            // 2048
    const int ch1 = M / S1;           // 256
    const int ch2 = M / S2;           // 256

    // Workspace: mins 2MB + bound 64KB + cd2 6.3MB + cidx 6.3MB = 14.7MB.
    char* p = (char*)d_ws;
    float* mins = (float*)p;  p += (size_t)Gt * S1 * sizeof(float);
    float* bnd  = (float*)p;  p += (size_t)Gt * sizeof(float);
    float* cd2  = (float*)p;  p += (size_t)Gt * S2 * 3 * sizeof(float);
    int*   cidx = (int*)p;

    dim3 gr1(G / (BLK * NG1), B, S1);   // (4, 8, 32) = 1024 blocks
    knn_min<<<gr1, BLK, 0, stream>>>(mesh_pos, grid_pos, mins, M, G, Gt, ch1);

    knn_bound<<<Gt / BLK, BLK, 0, stream>>>(mins, bnd, Gt);

    dim3 gr3(G / BLK, B, S2);           // (8, 8, 32) = 2048 blocks
    knn_scan<<<gr3, BLK, 0, stream>>>(mesh_pos, grid_pos, bnd, cd2, cidx, M, G, Gt, ch2);

    knn_merge<<<Gt / 4, BLK, 0, stream>>>(x, cd2, cidx, (float*)d_out, M, G, Gt);
}

// Round 9
// 88.895 us; speedup vs baseline: 1.0685x; 1.0685x over previous
//
#include <hip/hip_runtime.h>

// CfdInterpolateMeshToGrid: B=8, M=8192 mesh pts/batch, G=2048 grid pts/batch,
// D=2, C=64, K=3.  out[g,c] = sum_k w_k * x[nn_k(g), c] / sum_k w_k,
// w_k = 1 / max(d2_k, 1e-16), d2 = (g2 + m2) - 2*dot.
//
// NUMERICS (locked by rounds 1-5 — DO NOT CHANGE):
//   #pragma clang fp contract(off) in every kernel, plus exactly:
//     m2  = (mx*mx) + (my*my)           // unfused
//     g2  = (gx*gx) + (gy*gy)           // unfused
//     p0  = gx*mx; dot = fmaf(gy,my,p0) // fma-ascending k-contraction (BLAS)
//     t   = g2 + m2
//     d2  = fmaf(-2, dot, t)            // == t - (2*dot) bit-exactly (r7 ok)
//   Top-3 by strict < on d2, lowest-global-index wins ties (stable top_k).
//
// SCHEDULE (round 9): rounds 7-8 proved the scan loops are LDS-PIPE-bound:
// one broadcast ds_read_b128 (~12 cyc on the CU's single LDS port) feeds only
// 64 pairs/wave-iter; floor = 2.1M reads x 12cyc / 256CU = 41us. Fix: NG=4
// grid points per thread -> one read feeds 256 pairs (LDS /4), VALU/LDS
// co-bound at ~4x throughput. Merge: candidates staged into LDS with a
// coalesced [s]-segment mapping (its scattered 192KB-stride reads were the
// round-8 straggler), butterfly fed from LDS.

#define BLK 256
#define S1  32          // phase-1 chunks (chunkLen 256)
#define S2  32          // phase-2 chunks (chunkLen 256)
#define NG  4           // grid points per thread (both scan kernels)
#define PADIDX 0x7FFFFFFF

// Phase 1: branchless chunk-min of d2. block = (gb, b, s); each thread owns
// NG grid points spaced BLK apart (coalesced loads/stores).
__global__ void knn_min(const float* __restrict__ mesh_pos,
                        const float* __restrict__ grid_pos,
                        float* __restrict__ mins,
                        int M, int G, int Gt, int chunkLen)
{
#pragma clang fp contract(off)
    __shared__ float4 lds[256];
    const int gb = blockIdx.x, b = blockIdx.y, s = blockIdx.z;
    const int tid = threadIdx.x;

    const float2* mp = (const float2*)mesh_pos + (size_t)b * M + (size_t)s * chunkLen;
    for (int j = tid; j < chunkLen; j += BLK) {
        float2 m = mp[j];
        float m2 = (m.x * m.x) + (m.y * m.y);   // unfused (contract off)
        lds[j] = make_float4(m.x, m.y, m2, 0.0f);
    }
    __syncthreads();

    const int gbase = b * G + gb * (BLK * NG) + tid;
    float gx[NG], gy[NG], g2[NG], mn[NG];
    #pragma unroll
    for (int k = 0; k < NG; ++k) {
        float2 gp = ((const float2*)grid_pos)[gbase + k * BLK];
        gx[k] = gp.x; gy[k] = gp.y;
        g2[k] = (gp.x * gp.x) + (gp.y * gp.y);   // unfused
        mn[k] = 1e30f;
    }

    #pragma unroll 4
    for (int j = 0; j < chunkLen; ++j) {
        float4 m = lds[j];
        #pragma unroll
        for (int k = 0; k < NG; ++k) {
            float p0  = gx[k] * m.x;
            float dot = fmaf(gy[k], m.y, p0);
            float t   = g2[k] + m.z;
            float d2  = fmaf(-2.0f, dot, t);
            mn[k] = fminf(mn[k], d2);
        }
    }
    #pragma unroll
    for (int k = 0; k < NG; ++k)
        mins[(size_t)s * Gt + gbase + k * BLK] = mn[k];
}

// Bound: per grid point, 3rd-smallest of the S1 chunk mins. Provable upper
// bound on the 3rd-NN d2 (the 3 best chunk-mins are 3 distinct points).
__global__ void knn_bound(const float* __restrict__ mins,
                          float* __restrict__ bound, int Gt)
{
    const int g = blockIdx.x * BLK + threadIdx.x;
    float b0 = 1e30f, b1 = 1e30f, b2 = 1e30f;
    #pragma unroll
    for (int s = 0; s < S1; ++s) {
        float v = mins[(size_t)s * Gt + g];
        if (v < b2) {
            if (v < b1) { b2 = b1; if (v < b0) { b1 = b0; b0 = v; } else b1 = v; }
            else        { b2 = v; }
        }
    }
    bound[g] = b2;
}

// Phase 2: gated rescan, NG grid points per thread; per-chunk top-3 of
// candidates with d2 <= bound. Wave-uniform gate -> insert chain cold.
__global__ void knn_scan(const float* __restrict__ mesh_pos,
                         const float* __restrict__ grid_pos,
                         const float* __restrict__ bound,
                         float* __restrict__ cd2,
                         int* __restrict__ cidx,
                         int M, int G, int Gt, int chunkLen)
{
#pragma clang fp contract(off)
    __shared__ float4 lds[256];
    const int gb = blockIdx.x, b = blockIdx.y, s = blockIdx.z;
    const int tid = threadIdx.x;

    const float2* mp = (const float2*)mesh_pos + (size_t)b * M + (size_t)s * chunkLen;
    for (int j = tid; j < chunkLen; j += BLK) {
        float2 m = mp[j];
        float m2 = (m.x * m.x) + (m.y * m.y);   // unfused — identical to phase 1
        lds[j] = make_float4(m.x, m.y, m2, 0.0f);
    }
    __syncthreads();

    const int gbase = b * G + gb * (BLK * NG) + tid;
    float gx[NG], gy[NG], g2[NG], bnd[NG];
    float t0[NG], t1[NG], t2[NG];
    int   i0[NG], i1[NG], i2[NG];
    #pragma unroll
    for (int k = 0; k < NG; ++k) {
        float2 gp = ((const float2*)grid_pos)[gbase + k * BLK];
        gx[k] = gp.x; gy[k] = gp.y;
        g2[k] = (gp.x * gp.x) + (gp.y * gp.y);   // unfused
        bnd[k] = bound[gbase + k * BLK];
        t0[k] = 1e30f; t1[k] = 1e30f; t2[k] = 1e30f;
        i0[k] = PADIDX; i1[k] = PADIDX; i2[k] = PADIDX;
    }

    #pragma unroll 2
    for (int j = 0; j < chunkLen; ++j) {
        float4 m = lds[j];
        float d2v[NG];
        bool  h[NG];
        #pragma unroll
        for (int k = 0; k < NG; ++k) {
            float p0  = gx[k] * m.x;
            float dot = fmaf(gy[k], m.y, p0);
            float t   = g2[k] + m.z;
            d2v[k]    = fmaf(-2.0f, dot, t);
            h[k]      = (d2v[k] <= bnd[k]);
        }
        if (__any(h[0] | h[1] | h[2] | h[3])) {   // wave-uniform, rare (~5%)
            #pragma unroll
            for (int k = 0; k < NG; ++k) {
                if (h[k]) {
                    float d2 = d2v[k];
                    if (d2 < t2[k]) {
                        if (d2 < t1[k]) {
                            t2[k] = t1[k]; i2[k] = i1[k];
                            if (d2 < t0[k]) { t1[k] = t0[k]; i1[k] = i0[k]; t0[k] = d2; i0[k] = j; }
                            else            { t1[k] = d2; i1[k] = j; }
                        } else              { t2[k] = d2; i2[k] = j; }
                    }
                }
            }
        }
    }

    const int joff = s * chunkLen;
    #pragma unroll
    for (int k = 0; k < NG; ++k) {
        const size_t base = ((size_t)s * Gt + gbase + k * BLK) * 3;
        cd2[base + 0] = t0[k]; cidx[base + 0] = (i0[k] == PADIDX) ? PADIDX : i0[k] + joff;
        cd2[base + 1] = t1[k]; cidx[base + 1] = (i1[k] == PADIDX) ? PADIDX : i1[k] + joff;
        cd2[base + 2] = t2[k]; cidx[base + 2] = (i2[k] == PADIDX) ? PADIDX : i2[k] + joff;
    }
}

// Merge + gather: block = 4 grid points, one wave each. Candidates staged
// into LDS coalesced (for fixed s, the 12 floats covering g0..g0+3 are
// contiguous), then 96-way butterfly lex-min extraction ((d2, idx) order
// reproduces stable top_k), then lane=channel gather + locked epilogue.
__global__ void knn_merge(const float* __restrict__ x,
                          const float* __restrict__ cd2,
                          const int* __restrict__ cidx,
                          float* __restrict__ out,
                          int M, int G, int Gt)
{
#pragma clang fp contract(off)
    __shared__ float sd2[4 * 96];
    __shared__ int   sidx[4 * 96];
    const int tid = threadIdx.x;
    const int g0  = blockIdx.x * 4;

    for (int e = tid; e < S2 * 12; e += BLK) {      // 384 elements
        const int s = e / 12, r = e - 12 * s;
        const int gg = r / 3, k = r - 3 * gg;
        const size_t a = ((size_t)s * Gt + g0 + gg) * 3 + k;
        sd2 [gg * 96 + s * 3 + k] = cd2[a];
        sidx[gg * 96 + s * 3 + k] = cidx[a];
    }
    __syncthreads();

    const int w = tid >> 6, lane = tid & 63;
    const int g = g0 + w;

    float da = sd2[w * 96 + lane];
    int   ia = sidx[w * 96 + lane];
    float db = 1e30f; int ib = PADIDX;
    if (lane < 32) { db = sd2[w * 96 + 64 + lane]; ib = sidx[w * 96 + 64 + lane]; }

    float wd2[3]; int widx[3];
    #pragma unroll
    for (int r = 0; r < 3; ++r) {
        float rd; int ri;
        if (db < da || (db == da && ib < ia)) { rd = db; ri = ib; }
        else                                  { rd = da; ri = ia; }
        #pragma unroll
        for (int off = 32; off; off >>= 1) {
            float od = __shfl_xor(rd, off, 64);
            int   oi = __shfl_xor(ri, off, 64);
            if (od < rd || (od == rd && oi < ri)) { rd = od; ri = oi; }
        }
        wd2[r] = rd; widx[r] = ri;
        if (da == rd && ia == ri)      { da = 1e30f; ia = PADIDX; }
        else if (db == rd && ib == ri) { db = 1e30f; ib = PADIDX; }
    }

    const int b = g / G;
    const float w0 = 1.0f / fmaxf(wd2[0], 1e-16f);
    const float w1 = 1.0f / fmaxf(wd2[1], 1e-16f);
    const float w2 = 1.0f / fmaxf(wd2[2], 1e-16f);

    const size_t rowBase = (size_t)b * M * 64;
    const float x0 = x[rowBase + (size_t)widx[0] * 64 + lane];
    const float x1 = x[rowBase + (size_t)widx[1] * 64 + lane];
    const float x2 = x[rowBase + (size_t)widx[2] * 64 + lane];

    const float num = ((w0 * x0) + (w1 * x1)) + (w2 * x2);  // unfused
    const float den = (w0 + w1) + w2;
    out[(size_t)g * 64 + lane] = num / den;
}

extern "C" void kernel_launch(void* const* d_in, const int* in_sizes, int n_in,
                              void* d_out, int out_size, void* d_ws, size_t ws_size,
                              hipStream_t stream) {
    const float* x        = (const float*)d_in[0];
    const float* mesh_pos = (const float*)d_in[1];
    const float* grid_pos = (const float*)d_in[2];
    // d_in[3] = batch_idx (int64) — contiguous repeat layout, unused.

    const int N  = in_sizes[1] / 2;   // 65536
    const int Gt = in_sizes[2] / 2;   // 16384
    const int B  = 8;
    const int M  = N / B;             // 8192
    const int G  = Gt / B;            // 2048
    const int ch1 = M / S1;           // 256
    const int ch2 = M / S2;           // 256

    // Workspace: mins 2MB + bound 64KB + cd2 6.3MB + cidx 6.3MB = 14.7MB
    // (same footprint as round 8, which fit).
    char* p = (char*)d_ws;
    float* mins = (float*)p;  p += (size_t)Gt * S1 * sizeof(float);
    float* bnd  = (float*)p;  p += (size_t)Gt * sizeof(float);
    float* cd2  = (float*)p;  p += (size_t)Gt * S2 * 3 * sizeof(float);
    int*   cidx = (int*)p;

    dim3 gr1(G / (BLK * NG), B, S1);    // (2, 8, 32) = 512 blocks
    knn_min<<<gr1, BLK, 0, stream>>>(mesh_pos, grid_pos, mins, M, G, Gt, ch1);

    knn_bound<<<Gt / BLK, BLK, 0, stream>>>(mins, bnd, Gt);

    dim3 gr3(G / (BLK * NG), B, S2);    // (2, 8, 32) = 512 blocks
    knn_scan<<<gr3, BLK, 0, stream>>>(mesh_pos, grid_pos, bnd, cd2, cidx, M, G, Gt, ch2);

    knn_merge<<<Gt / 4, BLK, 0, stream>>>(x, cd2, cidx, (float*)d_out, M, G, Gt);
}

// Round 10
// 39.879 us; speedup vs baseline: 2.3818x; 2.2291x over previous
//
#include <hip/hip_runtime.h>

// CfdInterpolateMeshToGrid: B=8, M=8192 mesh pts/batch, G=2048 grid pts/batch,
// D=2, C=64, K=3.  out[g,c] = sum_k w_k * x[nn_k(g), c] / sum_k w_k,
// w_k = 1 / max(d2_k, 1e-16), d2 = (g2 + m2) - 2*dot.
//
// NUMERICS (locked by rounds 1-5 — DO NOT CHANGE):
//   #pragma clang fp contract(off) in every kernel, plus exactly:
//     m2  = (mx*mx) + (my*my)           // unfused
//     g2  = (gx*gx) + (gy*gy)           // unfused
//     p0  = gx*mx; dot = fmaf(gy,my,p0) // fma-ascending k-contraction (BLAS)
//     t   = g2 + m2
//     d2  = fmaf(-2, dot, t)            // == t - (2*dot) bit-exactly (r7 ok)
//   Top-3 by strict < on d2, lowest-global-index wins ties (stable top_k).
//
// SCHEDULE (round 10):
//  - r9 lesson: NG=4 needs >=4 blocks/CU for latency hiding (16 waves/CU gave
//    88% VALUBusy in r6; 8 waves/CU gave 44-48% in r8/r9). knn_min now
//    S1=64 chunks x chunkLen 128, grid (2,8,64)=1024 blocks.
//  - Phase 2 restructured: a chunk can hold a top-3 point only if its
//    chunk-min <= bnd (= 3rd-smallest chunk-min) -> ~3 of 64 chunks qualify.
//    knn_final (wave per grid point): butterfly top-3 of the 64 chunk-mins
//    -> bnd + ballot mask; scan only masked chunks from L2 (mesh is 512KB,
//    resident); per-lane sorted top-3; lex-(d2,idx) butterfly merge = stable
//    top_k; coalesced x-gather; locked epilogue. Replaces the full 134M-pair
//    rescan + merge kernels (~60us) with ~5us.

#define BLK 256
#define S1  64          // chunks per batch
#define CH  128         // chunk length = M/S1
#define NG  4           // grid points per thread in knn_min
#define PADIDX 0x7FFFFFFF

// Kernel 1: branchless chunk-min of d2. block = (gb, b, s).
__global__ void knn_min(const float* __restrict__ mesh_pos,
                        const float* __restrict__ grid_pos,
                        float* __restrict__ mins,
                        int M, int G, int Gt)
{
#pragma clang fp contract(off)
    __shared__ float4 lds[CH];
    const int gb = blockIdx.x, b = blockIdx.y, s = blockIdx.z;
    const int tid = threadIdx.x;

    const float2* mp = (const float2*)mesh_pos + (size_t)b * M + (size_t)s * CH;
    if (tid < CH) {
        float2 m = mp[tid];
        float m2 = (m.x * m.x) + (m.y * m.y);   // unfused (contract off)
        lds[tid] = make_float4(m.x, m.y, m2, 0.0f);
    }
    __syncthreads();

    const int gbase = b * G + gb * (BLK * NG) + tid;
    float gx[NG], gy[NG], g2[NG], mn[NG];
    #pragma unroll
    for (int k = 0; k < NG; ++k) {
        float2 gp = ((const float2*)grid_pos)[gbase + k * BLK];
        gx[k] = gp.x; gy[k] = gp.y;
        g2[k] = (gp.x * gp.x) + (gp.y * gp.y);   // unfused
        mn[k] = 1e30f;
    }

    #pragma unroll 4
    for (int j = 0; j < CH; ++j) {
        float4 m = lds[j];
        #pragma unroll
        for (int k = 0; k < NG; ++k) {
            float p0  = gx[k] * m.x;
            float dot = fmaf(gy[k], m.y, p0);
            float t   = g2[k] + m.z;
            float d2  = fmaf(-2.0f, dot, t);
            mn[k] = fminf(mn[k], d2);
        }
    }
    #pragma unroll
    for (int k = 0; k < NG; ++k)
        mins[(size_t)s * Gt + gbase + k * BLK] = mn[k];
}

// Kernel 2: fused bound + masked scan + merge + gather. One wave / grid pt.
__global__ void knn_final(const float* __restrict__ x,
                          const float* __restrict__ mesh_pos,
                          const float* __restrict__ grid_pos,
                          const float* __restrict__ mins,
                          float* __restrict__ out,
                          int M, int G, int Gt)
{
#pragma clang fp contract(off)
    const int tid  = threadIdx.x;
    const int g    = blockIdx.x * 4 + (tid >> 6);
    const int lane = tid & 63;
    const int b    = g / G;

    // --- bound: 3rd-smallest of the 64 chunk mins (lane = chunk) ---------
    // Lex (val, lane) extraction pops exactly one holder per round -> exact.
    const float mv = mins[(size_t)lane * Gt + g];
    float cur = mv; int cl = lane;
    float bnd = 1e30f;
    #pragma unroll
    for (int r = 0; r < 3; ++r) {
        float rd = cur; int ri = cl;
        #pragma unroll
        for (int off = 32; off; off >>= 1) {
            float od = __shfl_xor(rd, off, 64);
            int   oi = __shfl_xor(ri, off, 64);
            if (od < rd || (od == rd && oi < ri)) { rd = od; ri = oi; }
        }
        bnd = rd;
        if (cur == rd && cl == ri) { cur = 1e30f; cl = 64; }
    }
    // Chunks that can contain a top-3 point: chunk-min <= bnd (~3 of 64).
    unsigned long long mk = __ballot(mv <= bnd);

    // --- masked scan: per-lane sorted top-3 over qualifying chunks -------
    const float2 gp = ((const float2*)grid_pos)[g];
    const float gx = gp.x, gy = gp.y;
    const float g2 = (gx * gx) + (gy * gy);      // unfused

    float d0 = 1e30f, d1 = 1e30f, d2s = 1e30f;
    int   i0 = PADIDX, i1 = PADIDX, i2 = PADIDX;

    const float4* mp4 = (const float4*)((const float2*)mesh_pos + (size_t)b * M);
    while (mk) {
        const int s = __builtin_ctzll(mk); mk &= mk - 1;   // ascending chunks
        const float4 v = mp4[s * (CH / 2) + lane];         // pts 2*lane, 2*lane+1
        const int idxA = s * CH + 2 * lane;
        // point A (visited before B: ascending index within lane)
        {
            float m2  = (v.x * v.x) + (v.y * v.y);         // unfused
            float p0  = gx * v.x;
            float dot = fmaf(gy, v.y, p0);
            float t   = g2 + m2;
            float d2  = fmaf(-2.0f, dot, t);
            if (d2 < d2s) {
                if (d2 < d1) {
                    d2s = d1; i2 = i1;
                    if (d2 < d0) { d1 = d0; i1 = i0; d0 = d2; i0 = idxA; }
                    else         { d1 = d2; i1 = idxA; }
                } else           { d2s = d2; i2 = idxA; }
            }
        }
        // point B
        {
            float m2  = (v.z * v.z) + (v.w * v.w);         // unfused
            float p0  = gx * v.z;
            float dot = fmaf(gy, v.w, p0);
            float t   = g2 + m2;
            float d2  = fmaf(-2.0f, dot, t);
            if (d2 < d2s) {
                if (d2 < d1) {
                    d2s = d1; i2 = i1;
                    if (d2 < d0) { d1 = d0; i1 = i0; d0 = d2; i0 = idxA + 1; }
                    else         { d1 = d2; i1 = idxA + 1; }
                } else           { d2s = d2; i2 = idxA + 1; }
            }
        }
    }

    // --- merge: global top-3 from 64 lanes x sorted-3 slots ---------------
    // (d2, idx) lex order == stable top_k (idx unique for real candidates;
    // pads (1e30, PADIDX) never win: >=3 chunks x 128 real points scanned).
    float wd[3]; int wi[3];
    #pragma unroll
    for (int r = 0; r < 3; ++r) {
        float rd = d0; int ri = i0;    // lane candidate = best remaining slot
        #pragma unroll
        for (int off = 32; off; off >>= 1) {
            float od = __shfl_xor(rd, off, 64);
            int   oi = __shfl_xor(ri, off, 64);
            if (od < rd || (od == rd && oi < ri)) { rd = od; ri = oi; }
        }
        wd[r] = rd; wi[r] = ri;
        if (d0 == rd && i0 == ri) {    // pop my slot, shift up
            d0 = d1; i0 = i1; d1 = d2s; i1 = i2; d2s = 1e30f; i2 = PADIDX;
        }
    }

    // --- locked epilogue ---------------------------------------------------
    const float w0 = 1.0f / fmaxf(wd[0], 1e-16f);
    const float w1 = 1.0f / fmaxf(wd[1], 1e-16f);
    const float w2 = 1.0f / fmaxf(wd[2], 1e-16f);

    const size_t rowBase = (size_t)b * M * 64;
    const float x0 = x[rowBase + (size_t)wi[0] * 64 + lane];
    const float x1 = x[rowBase + (size_t)wi[1] * 64 + lane];
    const float x2 = x[rowBase + (size_t)wi[2] * 64 + lane];

    const float num = ((w0 * x0) + (w1 * x1)) + (w2 * x2);  // unfused
    const float den = (w0 + w1) + w2;
    out[(size_t)g * 64 + lane] = num / den;
}

extern "C" void kernel_launch(void* const* d_in, const int* in_sizes, int n_in,
                              void* d_out, int out_size, void* d_ws, size_t ws_size,
                              hipStream_t stream) {
    const float* x        = (const float*)d_in[0];
    const float* mesh_pos = (const float*)d_in[1];
    const float* grid_pos = (const float*)d_in[2];
    // d_in[3] = batch_idx (int64) — contiguous repeat layout, unused.

    const int N  = in_sizes[1] / 2;   // 65536
    const int Gt = in_sizes[2] / 2;   // 16384
    const int B  = 8;
    const int M  = N / B;             // 8192
    const int G  = Gt / B;            // 2048

    // Workspace: mins = 64 x 16384 x 4B = 4 MB (fits; r8 used 14.7 MB).
    float* mins = (float*)d_ws;

    dim3 gr1(G / (BLK * NG), B, S1);    // (2, 8, 64) = 1024 blocks
    knn_min<<<gr1, BLK, 0, stream>>>(mesh_pos, grid_pos, mins, M, G, Gt);

    knn_final<<<Gt / 4, BLK, 0, stream>>>(x, mesh_pos, grid_pos, mins,
                                          (float*)d_out, M, G, Gt);
}

// Round 11
// 33.331 us; speedup vs baseline: 2.8497x; 1.1964x over previous
//
#include <hip/hip_runtime.h>

// CfdInterpolateMeshToGrid: B=8, M=8192 mesh pts/batch, G=2048 grid pts/batch,
// D=2, C=64, K=3.  out[g,c] = sum_k w_k * x[nn_k(g), c] / sum_k w_k,
// w_k = 1 / max(d2_k, 1e-16), d2 = (g2 + m2) - 2*dot.
//
// NUMERICS (locked by rounds 1-5 — DO NOT CHANGE):
//   #pragma clang fp contract(off), plus exactly:
//     m2  = (mx*mx) + (my*my)           // unfused
//     g2  = (gx*gx) + (gy*gy)           // unfused
//     p0  = gx*mx; dot = fmaf(gy,my,p0) // fma-ascending k-contraction (BLAS)
//     t   = g2 + m2
//     d2  = fmaf(-2, dot, t)            // == t - (2*dot) bit-exactly
//   Selection = 3 lex-smallest (d2, idx) — identical to stable top_k and
//   visit-order independent (safe with arbitrary bin scatter order).
//
// SCHEDULE (round 11): replace the 134M-pair brute-force phase 1 with
// spatial binning (positions are uniform in [0,1)^2):
//   zero -> histogram -> per-batch scan -> scatter -> fused search.
// Search: wave per grid point scans its 3x3 bin ring (~72 pts, 3 contiguous
// row segments of the sorted array). Containment proof: accept iff
// wd[2] + 1e-4 < dist^2(g, unexamined region); the examined rectangle extends
// >= 1 full bin (1/32) beyond g on every unclamped side, so bd2 >= 9.8e-4 vs
// typical 3rd-NN d2 ~ 1.2e-4. Margin 1e-4 >> 2e-6 abs f32 rounding of d2 ->
// no outside point can displace/tie a selected one. Rare fail (~corner
// voids) -> full 8192-pt fallback scan. Work: 134M -> ~1.2M pairs.

#define BLK 256
#define NB 32
#define NBINS (NB * NB)
#define PADIDX 0x7FFFFFFF
#define MARGIN 1e-4f

__global__ void bin_zero(int* __restrict__ hist) {
    hist[blockIdx.x * BLK + threadIdx.x] = 0;
}

__global__ void bin_hist(const float* __restrict__ mesh_pos,
                         int* __restrict__ hist, int M) {
    const int n = blockIdx.x * BLK + threadIdx.x;
    const float2 p = ((const float2*)mesh_pos)[n];
    const int b = n / M;
    const int bx = max(0, min((int)(p.x * (float)NB), NB - 1));
    const int by = max(0, min((int)(p.y * (float)NB), NB - 1));
    atomicAdd(&hist[b * NBINS + by * NB + bx], 1);
}

// One block (1024 threads) per batch: exclusive scan of 1024 bin counts.
__global__ void bin_scan(const int* __restrict__ hist,
                         int* __restrict__ starts,   // [B][NBINS+1]
                         int* __restrict__ cursor,   // [B][NBINS]
                         int M) {
    const int b = blockIdx.x, t = threadIdx.x;
    const int v = hist[b * NBINS + t];
    int sc = v;                                    // wave-inclusive scan
    #pragma unroll
    for (int off = 1; off < 64; off <<= 1) {
        int n = __shfl_up(sc, off, 64);
        if ((t & 63) >= off) sc += n;
    }
    __shared__ int wsum[16];
    __shared__ int woff[17];
    if ((t & 63) == 63) wsum[t >> 6] = sc;
    __syncthreads();
    if (t == 0) {
        int acc = 0;
        for (int i = 0; i < 16; ++i) { woff[i] = acc; acc += wsum[i]; }
        woff[16] = acc;
    }
    __syncthreads();
    const int excl = woff[t >> 6] + sc - v;
    starts[b * (NBINS + 1) + t] = excl;
    cursor[b * NBINS + t] = excl;
    if (t == 0) starts[b * (NBINS + 1) + NBINS] = woff[16];   // = M
}

__global__ void bin_scatter(const float* __restrict__ mesh_pos,
                            int* __restrict__ cursor,
                            float2* __restrict__ sxy,
                            int* __restrict__ sid, int M) {
    const int n = blockIdx.x * BLK + threadIdx.x;
    const float2 p = ((const float2*)mesh_pos)[n];
    const int b = n / M;
    const int bx = max(0, min((int)(p.x * (float)NB), NB - 1));
    const int by = max(0, min((int)(p.y * (float)NB), NB - 1));
    const int pos = atomicAdd(&cursor[b * NBINS + by * NB + bx], 1);
    sxy[(size_t)b * M + pos] = p;
    sid[(size_t)b * M + pos] = n - b * M;        // local index in batch
}

// lex-(d2, idx) sorted-3 insert; visit-order independent == stable top_k.
#define LEX_INSERT(d2, idx)                                                  \
    if ((d2) < t2 || ((d2) == t2 && (idx) < i2)) {                           \
        if ((d2) < t1 || ((d2) == t1 && (idx) < i1)) {                       \
            t2 = t1; i2 = i1;                                                \
            if ((d2) < t0 || ((d2) == t0 && (idx) < i0)) {                   \
                t1 = t0; i1 = i0; t0 = (d2); i0 = (idx);                     \
            } else { t1 = (d2); i1 = (idx); }                                \
        } else { t2 = (d2); i2 = (idx); }                                    \
    }

#define BFLY_EXTRACT(wd, wi)                                                 \
    _Pragma("unroll")                                                        \
    for (int r = 0; r < 3; ++r) {                                            \
        float rd = t0; int ri = i0;                                          \
        _Pragma("unroll")                                                    \
        for (int off = 32; off; off >>= 1) {                                 \
            float od = __shfl_xor(rd, off, 64);                              \
            int   oi = __shfl_xor(ri, off, 64);                              \
            if (od < rd || (od == rd && oi < ri)) { rd = od; ri = oi; }      \
        }                                                                    \
        wd[r] = rd; wi[r] = ri;                                              \
        if (t0 == rd && i0 == ri) {                                          \
            t0 = t1; i0 = i1; t1 = t2; i1 = i2; t2 = 1e30f; i2 = PADIDX;     \
        }                                                                    \
    }

// Fused search + merge + gather. One wave per grid point.
__global__ void knn_search(const float* __restrict__ x,
                           const float* __restrict__ grid_pos,
                           const float2* __restrict__ sxy,
                           const int* __restrict__ sid,
                           const int* __restrict__ starts,
                           float* __restrict__ out,
                           int M, int G)
{
#pragma clang fp contract(off)
    const int tid  = threadIdx.x;
    const int g    = blockIdx.x * 4 + (tid >> 6);
    const int lane = tid & 63;
    const int b    = g / G;

    const float2 gp = ((const float2*)grid_pos)[g];
    const float gx = gp.x, gy = gp.y;
    const float g2 = (gx * gx) + (gy * gy);          // unfused

    const int gbx = max(0, min((int)(gx * (float)NB), NB - 1));
    const int gby = max(0, min((int)(gy * (float)NB), NB - 1));
    const int bxlo = max(gbx - 1, 0), bxhi = min(gbx + 1, NB - 1);
    const int bylo = max(gby - 1, 0), byhi = min(gby + 1, NB - 1);

    // Ring = up to 3 contiguous segments (bins row-major: by*NB+bx).
    const int* st = starts + b * (NBINS + 1);
    int slo[3], cnt[3], nrows = 0;
    for (int ry = bylo; ry <= byhi; ++ry) {
        const int lo = st[ry * NB + bxlo];
        const int hi = st[ry * NB + bxhi + 1];
        slo[nrows] = lo; cnt[nrows] = hi - lo; ++nrows;
    }
    const int c0 = cnt[0];
    const int c1 = c0 + ((nrows > 1) ? cnt[1] : 0);
    const int T  = c1 + ((nrows > 2) ? cnt[2] : 0);

    const float2* bxy = sxy + (size_t)b * M;
    const int*    bid = sid + (size_t)b * M;

    float t0 = 1e30f, t1 = 1e30f, t2 = 1e30f;
    int   i0 = PADIDX, i1 = PADIDX, i2 = PADIDX;

    for (int base = 0; base < T; base += 64) {
        const int L = base + lane;
        if (L < T) {
            int r, off;
            if (L >= c1)      { r = 2; off = L - c1; }
            else if (L >= c0) { r = 1; off = L - c0; }
            else              { r = 0; off = L; }
            const int sp = slo[r] + off;
            const float2 mpt = bxy[sp];
            const int    idx = bid[sp];
            const float m2  = (mpt.x * mpt.x) + (mpt.y * mpt.y);  // unfused
            const float p0  = gx * mpt.x;
            const float dot = fmaf(gy, mpt.y, p0);
            const float t   = g2 + m2;
            const float d2  = fmaf(-2.0f, dot, t);
            LEX_INSERT(d2, idx)
        }
    }

    float wd[3]; int wi[3];
    BFLY_EXTRACT(wd, wi)

    // Containment check (wave-uniform): distance to unexamined region.
    const float w = 1.0f / (float)NB;
    const float dl = (bxlo > 0)      ? (gx - (float)bxlo * w)       : 1e30f;
    const float dr = (bxhi < NB - 1) ? ((float)(bxhi + 1) * w - gx) : 1e30f;
    const float dn = (bylo > 0)      ? (gy - (float)bylo * w)       : 1e30f;
    const float dt = (byhi < NB - 1) ? ((float)(byhi + 1) * w - gy) : 1e30f;
    const float bdd = fminf(fminf(dl, dr), fminf(dn, dt));
    const float bd2 = bdd * bdd;

    if (!(wd[2] + MARGIN < bd2)) {
        // Rare fallback (~corner voids): exact full-batch scan.
        t0 = t1 = t2 = 1e30f; i0 = i1 = i2 = PADIDX;
        for (int j = lane; j < M; j += 64) {
            const float2 mpt = bxy[j];
            const int    idx = bid[j];
            const float m2  = (mpt.x * mpt.x) + (mpt.y * mpt.y);  // unfused
            const float p0  = gx * mpt.x;
            const float dot = fmaf(gy, mpt.y, p0);
            const float t   = g2 + m2;
            const float d2  = fmaf(-2.0f, dot, t);
            LEX_INSERT(d2, idx)
        }
        BFLY_EXTRACT(wd, wi)
    }

    // Locked epilogue.
    const float w0 = 1.0f / fmaxf(wd[0], 1e-16f);
    const float w1 = 1.0f / fmaxf(wd[1], 1e-16f);
    const float w2 = 1.0f / fmaxf(wd[2], 1e-16f);

    const size_t rowBase = (size_t)b * M * 64;
    const float x0 = x[rowBase + (size_t)wi[0] * 64 + lane];
    const float x1 = x[rowBase + (size_t)wi[1] * 64 + lane];
    const float x2 = x[rowBase + (size_t)wi[2] * 64 + lane];

    const float num = ((w0 * x0) + (w1 * x1)) + (w2 * x2);   // unfused
    const float den = (w0 + w1) + w2;
    out[(size_t)g * 64 + lane] = num / den;
}

extern "C" void kernel_launch(void* const* d_in, const int* in_sizes, int n_in,
                              void* d_out, int out_size, void* d_ws, size_t ws_size,
                              hipStream_t stream) {
    const float* x        = (const float*)d_in[0];
    const float* mesh_pos = (const float*)d_in[1];
    const float* grid_pos = (const float*)d_in[2];
    // d_in[3] = batch_idx (int64) — contiguous repeat layout, unused.

    const int N  = in_sizes[1] / 2;   // 65536
    const int Gt = in_sizes[2] / 2;   // 16384
    const int B  = 8;
    const int M  = N / B;             // 8192
    const int G  = Gt / B;            // 2048

    // Workspace (< 1 MB): hist, starts, cursor, sorted xy, sorted id.
    char* p = (char*)d_ws;
    int*    hist   = (int*)p;     p += (size_t)B * NBINS * sizeof(int);
    int*    starts = (int*)p;     p += (size_t)B * (NBINS + 1) * sizeof(int);
    int*    cursor = (int*)p;     p += (size_t)B * NBINS * sizeof(int);
    float2* sxy    = (float2*)p;  p += (size_t)N * sizeof(float2);
    int*    sid    = (int*)p;

    bin_zero   <<<(B * NBINS) / BLK, BLK, 0, stream>>>(hist);
    bin_hist   <<<N / BLK, BLK, 0, stream>>>(mesh_pos, hist, M);
    bin_scan   <<<B, 1024, 0, stream>>>(hist, starts, cursor, M);
    bin_scatter<<<N / BLK, BLK, 0, stream>>>(mesh_pos, cursor, sxy, sid, M);
    knn_search <<<Gt / 4, BLK, 0, stream>>>(x, grid_pos, sxy, sid, starts,
                                            (float*)d_out, M, G);
}

// Round 12
// 32.902 us; speedup vs baseline: 2.8869x; 1.0131x over previous
//
#include <hip/hip_runtime.h>

// CfdInterpolateMeshToGrid: B=8, M=8192 mesh pts/batch, G=2048 grid pts/batch,
// D=2, C=64, K=3.  out[g,c] = sum_k w_k * x[nn_k(g), c] / sum_k w_k,
// w_k = 1 / max(d2_k, 1e-16), d2 = (g2 + m2) - 2*dot.
//
// NUMERICS (locked by rounds 1-5 — DO NOT CHANGE):
//   #pragma clang fp contract(off), plus exactly:
//     m2  = (mx*mx) + (my*my)           // unfused
//     g2  = (gx*gx) + (gy*gy)           // unfused
//     p0  = gx*mx; dot = fmaf(gy,my,p0) // fma-ascending k-contraction (BLAS)
//     t   = g2 + m2
//     d2  = fmaf(-2, dot, t)            // == t - (2*dot) bit-exactly
//   Selection = 3 lex-smallest (d2, idx) — identical to stable top_k and
//   visit-order independent (safe with nondeterministic bin scatter order;
//   OUTPUT stays deterministic: selection depends only on the candidate set).
//
// SCHEDULE (round 12): round 11 = 33.3us across 5 kernels; the binning chain
// (zero/hist/scan/scatter, each ~1-3us of work) paid ~4 launch gaps. Fused
// into ONE kernel bin_all: block = batch (8 blocks x 1024 threads), LDS
// histogram -> in-block scan -> LDS-cursor scatter (positions reloaded from
// L2 in the scatter phase; no runtime-indexed register arrays). knn_search
// unchanged from round 11 (passed, bit-stable). 5 kernels -> 2.

#define BLK 256
#define NTB 1024
#define NB 32
#define NBINS (NB * NB)
#define PADIDX 0x7FFFFFFF
#define MARGIN 1e-4f

// One block per batch: zero + histogram + exclusive scan + scatter.
__global__ void bin_all(const float* __restrict__ mesh_pos,
                        int* __restrict__ starts,    // [B][NBINS+1]
                        float2* __restrict__ sxy,
                        int* __restrict__ sid, int M)
{
    __shared__ int h[NBINS];          // histogram, then cursor
    __shared__ int wsum[16];
    __shared__ int woff[17];
    const int b = blockIdx.x, t = threadIdx.x;

    h[t] = 0;                         // NBINS == NTB == 1024
    __syncthreads();

    const float2* mp = (const float2*)mesh_pos + (size_t)b * M;
    for (int n = t; n < M; n += NTB) {
        const float2 p = mp[n];
        const int bx = max(0, min((int)(p.x * (float)NB), NB - 1));
        const int by = max(0, min((int)(p.y * (float)NB), NB - 1));
        atomicAdd(&h[by * NB + bx], 1);
    }
    __syncthreads();

    const int v = h[t];
    int sc = v;                       // wave-inclusive scan
    #pragma unroll
    for (int off = 1; off < 64; off <<= 1) {
        int nv = __shfl_up(sc, off, 64);
        if ((t & 63) >= off) sc += nv;
    }
    if ((t & 63) == 63) wsum[t >> 6] = sc;
    __syncthreads();
    if (t == 0) {
        int acc = 0;
        #pragma unroll
        for (int i = 0; i < 16; ++i) { woff[i] = acc; acc += wsum[i]; }
        woff[16] = acc;
    }
    __syncthreads();
    const int excl = woff[t >> 6] + sc - v;
    starts[b * (NBINS + 1) + t] = excl;
    if (t == 0) starts[b * (NBINS + 1) + NBINS] = woff[16];   // = M
    __syncthreads();                  // everyone done reading h[t]
    h[t] = excl;                      // cursor
    __syncthreads();

    for (int n = t; n < M; n += NTB) {
        const float2 p = mp[n];       // L1/L2 hit (just streamed)
        const int bx = max(0, min((int)(p.x * (float)NB), NB - 1));
        const int by = max(0, min((int)(p.y * (float)NB), NB - 1));
        const int pos = atomicAdd(&h[by * NB + bx], 1);
        sxy[(size_t)b * M + pos] = p;
        sid[(size_t)b * M + pos] = n;             // batch-local index
    }
}

// lex-(d2, idx) sorted-3 insert; visit-order independent == stable top_k.
#define LEX_INSERT(d2, idx)                                                  \
    if ((d2) < t2 || ((d2) == t2 && (idx) < i2)) {                           \
        if ((d2) < t1 || ((d2) == t1 && (idx) < i1)) {                       \
            t2 = t1; i2 = i1;                                                \
            if ((d2) < t0 || ((d2) == t0 && (idx) < i0)) {                   \
                t1 = t0; i1 = i0; t0 = (d2); i0 = (idx);                     \
            } else { t1 = (d2); i1 = (idx); }                                \
        } else { t2 = (d2); i2 = (idx); }                                    \
    }

#define BFLY_EXTRACT(wd, wi)                                                 \
    _Pragma("unroll")                                                        \
    for (int r = 0; r < 3; ++r) {                                            \
        float rd = t0; int ri = i0;                                          \
        _Pragma("unroll")                                                    \
        for (int off = 32; off; off >>= 1) {                                 \
            float od = __shfl_xor(rd, off, 64);                              \
            int   oi = __shfl_xor(ri, off, 64);                              \
            if (od < rd || (od == rd && oi < ri)) { rd = od; ri = oi; }      \
        }                                                                    \
        wd[r] = rd; wi[r] = ri;                                              \
        if (t0 == rd && i0 == ri) {                                          \
            t0 = t1; i0 = i1; t1 = t2; i1 = i2; t2 = 1e30f; i2 = PADIDX;     \
        }                                                                    \
    }

// Fused search + merge + gather. One wave per grid point (r11, unchanged).
__global__ void knn_search(const float* __restrict__ x,
                           const float* __restrict__ grid_pos,
                           const float2* __restrict__ sxy,
                           const int* __restrict__ sid,
                           const int* __restrict__ starts,
                           float* __restrict__ out,
                           int M, int G)
{
#pragma clang fp contract(off)
    const int tid  = threadIdx.x;
    const int g    = blockIdx.x * 4 + (tid >> 6);
    const int lane = tid & 63;
    const int b    = g / G;

    const float2 gp = ((const float2*)grid_pos)[g];
    const float gx = gp.x, gy = gp.y;
    const float g2 = (gx * gx) + (gy * gy);          // unfused

    const int gbx = max(0, min((int)(gx * (float)NB), NB - 1));
    const int gby = max(0, min((int)(gy * (float)NB), NB - 1));
    const int bxlo = max(gbx - 1, 0), bxhi = min(gbx + 1, NB - 1);
    const int bylo = max(gby - 1, 0), byhi = min(gby + 1, NB - 1);

    // Ring = up to 3 contiguous segments (bins row-major: by*NB+bx).
    const int* st = starts + b * (NBINS + 1);
    int slo[3], cnt[3], nrows = 0;
    for (int ry = bylo; ry <= byhi; ++ry) {
        const int lo = st[ry * NB + bxlo];
        const int hi = st[ry * NB + bxhi + 1];
        slo[nrows] = lo; cnt[nrows] = hi - lo; ++nrows;
    }
    const int c0 = cnt[0];
    const int c1 = c0 + ((nrows > 1) ? cnt[1] : 0);
    const int T  = c1 + ((nrows > 2) ? cnt[2] : 0);

    const float2* bxy = sxy + (size_t)b * M;
    const int*    bid = sid + (size_t)b * M;

    float t0 = 1e30f, t1 = 1e30f, t2 = 1e30f;
    int   i0 = PADIDX, i1 = PADIDX, i2 = PADIDX;

    for (int base = 0; base < T; base += 64) {
        const int L = base + lane;
        if (L < T) {
            int r, off;
            if (L >= c1)      { r = 2; off = L - c1; }
            else if (L >= c0) { r = 1; off = L - c0; }
            else              { r = 0; off = L; }
            const int sp = slo[r] + off;
            const float2 mpt = bxy[sp];
            const int    idx = bid[sp];
            const float m2  = (mpt.x * mpt.x) + (mpt.y * mpt.y);  // unfused
            const float p0  = gx * mpt.x;
            const float dot = fmaf(gy, mpt.y, p0);
            const float t   = g2 + m2;
            const float d2  = fmaf(-2.0f, dot, t);
            LEX_INSERT(d2, idx)
        }
    }

    float wd[3]; int wi[3];
    BFLY_EXTRACT(wd, wi)

    // Containment check (wave-uniform): distance to unexamined region.
    const float w = 1.0f / (float)NB;
    const float dl = (bxlo > 0)      ? (gx - (float)bxlo * w)       : 1e30f;
    const float dr = (bxhi < NB - 1) ? ((float)(bxhi + 1) * w - gx) : 1e30f;
    const float dn = (bylo > 0)      ? (gy - (float)bylo * w)       : 1e30f;
    const float dt = (byhi < NB - 1) ? ((float)(byhi + 1) * w - gy) : 1e30f;
    const float bdd = fminf(fminf(dl, dr), fminf(dn, dt));
    const float bd2 = bdd * bdd;

    if (!(wd[2] + MARGIN < bd2)) {
        // Rare fallback (~corner voids): exact full-batch scan.
        t0 = t1 = t2 = 1e30f; i0 = i1 = i2 = PADIDX;
        for (int j = lane; j < M; j += 64) {
            const float2 mpt = bxy[j];
            const int    idx = bid[j];
            const float m2  = (mpt.x * mpt.x) + (mpt.y * mpt.y);  // unfused
            const float p0  = gx * mpt.x;
            const float dot = fmaf(gy, mpt.y, p0);
            const float t   = g2 + m2;
            const float d2  = fmaf(-2.0f, dot, t);
            LEX_INSERT(d2, idx)
        }
        BFLY_EXTRACT(wd, wi)
    }

    // Locked epilogue.
    const float w0 = 1.0f / fmaxf(wd[0], 1e-16f);
    const float w1 = 1.0f / fmaxf(wd[1], 1e-16f);
    const float w2 = 1.0f / fmaxf(wd[2], 1e-16f);

    const size_t rowBase = (size_t)b * M * 64;
    const float x0 = x[rowBase + (size_t)wi[0] * 64 + lane];
    const float x1 = x[rowBase + (size_t)wi[1] * 64 + lane];
    const float x2 = x[rowBase + (size_t)wi[2] * 64 + lane];

    const float num = ((w0 * x0) + (w1 * x1)) + (w2 * x2);   // unfused
    const float den = (w0 + w1) + w2;
    out[(size_t)g * 64 + lane] = num / den;
}

extern "C" void kernel_launch(void* const* d_in, const int* in_sizes, int n_in,
                              void* d_out, int out_size, void* d_ws, size_t ws_size,
                              hipStream_t stream) {
    const float* x        = (const float*)d_in[0];
    const float* mesh_pos = (const float*)d_in[1];
    const float* grid_pos = (const float*)d_in[2];
    // d_in[3] = batch_idx (int64) — contiguous repeat layout, unused.

    const int N  = in_sizes[1] / 2;   // 65536
    const int Gt = in_sizes[2] / 2;   // 16384
    const int B  = 8;
    const int M  = N / B;             // 8192
    const int G  = Gt / B;            // 2048

    // Workspace (< 1 MB): starts, sorted xy, sorted id.
    char* p = (char*)d_ws;
    int*    starts = (int*)p;     p += (size_t)B * (NBINS + 1) * sizeof(int);
    float2* sxy    = (float2*)p;  p += (size_t)N * sizeof(float2);
    int*    sid    = (int*)p;

    bin_all   <<<B, NTB, 0, stream>>>(mesh_pos, starts, sxy, sid, M);
    knn_search<<<Gt / 4, BLK, 0, stream>>>(x, grid_pos, sxy, sid, starts,
                                           (float*)d_out, M, G);
}